// Round 5
// baseline (1096.568 us; speedup 1.0000x reference)
//
#include <hip/hip_runtime.h>

#define NN 100000
#define NE 1600000
#define EPSV 1e-5f
#define SCHUNK 1024
#define SNB ((NN + SCHUNK - 1) / SCHUNK)  // 98
#define BNODES 200
#define NBUK (NN / BNODES)  // 500

typedef unsigned short u16;
typedef __attribute__((ext_vector_type(8))) short bf16x8;
typedef __attribute__((ext_vector_type(4))) float f32x4;

#define MFMA16(a, b, c) __builtin_amdgcn_mfma_f32_16x16x32_bf16(a, b, c, 0, 0, 0)

__device__ __forceinline__ u16 f2bf(float f) {
  unsigned u = __float_as_uint(f);
  unsigned r = u + 0x7fffu + ((u >> 16) & 1u);
  return (u16)(r >> 16);
}
__device__ __forceinline__ float b2f(u16 h) { return __uint_as_float(((unsigned)h) << 16); }
__device__ __forceinline__ float bflo(unsigned u) { return __uint_as_float(u << 16); }
__device__ __forceinline__ float bfhi(unsigned u) { return __uint_as_float(u & 0xffff0000u); }

// ---------- CSR build ----------
__global__ __launch_bounds__(256) void hist_k(const int* __restrict__ dst, int* __restrict__ cnt) {
  int e = blockIdx.x * 256 + threadIdx.x;
  if (e < NE) atomicAdd(&cnt[dst[e]], 1);
}

// hierarchical scan, phase 1: per-block sums of 1024-count chunks
__global__ __launch_bounds__(256) void scan1_k(const int* __restrict__ cnt, int* __restrict__ partial) {
  __shared__ int ws[4];
  const int t = threadIdx.x;
  const int base = blockIdx.x * SCHUNK;
  int s = 0;
  for (int i = t; i < SCHUNK; i += 256) {
    int idx = base + i;
    s += (idx < NN) ? cnt[idx] : 0;
  }
#pragma unroll
  for (int m = 1; m < 64; m <<= 1) s += __shfl_xor(s, m, 64);
  if ((t & 63) == 0) ws[t >> 6] = s;
  __syncthreads();
  if (t == 0) partial[blockIdx.x] = ws[0] + ws[1] + ws[2] + ws[3];
}

// phase 2: exclusive scan of the partials (single tiny block)
__global__ __launch_bounds__(128) void scan2_k(int* __restrict__ partial) {
  __shared__ int sm[128];
  const int t = threadIdx.x;
  int v = (t < SNB) ? partial[t] : 0;
  sm[t] = v;
  __syncthreads();
  for (int off = 1; off < 128; off <<= 1) {
    int u = (t >= off) ? sm[t - off] : 0;
    __syncthreads();
    sm[t] += u;
    __syncthreads();
  }
  if (t < SNB) partial[t] = sm[t] - v;
}

// phase 3: block-local scan + offset; writes row_ptr
__global__ __launch_bounds__(256) void scan3_k(const int* __restrict__ cnt, const int* __restrict__ partial,
                                               int* __restrict__ row_ptr) {
  __shared__ int sm[256];
  const int t = threadIdx.x;
  const int base = blockIdx.x * SCHUNK + t * 4;
  int c[4];
  int s = 0;
#pragma unroll
  for (int i = 0; i < 4; ++i) {
    int idx = base + i;
    c[i] = (idx < NN) ? cnt[idx] : 0;
    s += c[i];
  }
  sm[t] = s;
  __syncthreads();
  for (int off = 1; off < 256; off <<= 1) {
    int u = (t >= off) ? sm[t - off] : 0;
    __syncthreads();
    sm[t] += u;
    __syncthreads();
  }
  int run = partial[blockIdx.x] + sm[t] - s;
#pragma unroll
  for (int i = 0; i < 4; ++i) {
    int idx = base + i;
    if (idx < NN) {
      row_ptr[idx] = run;
      run += c[i];
    }
  }
  if (blockIdx.x == 0 && t == 0) row_ptr[NN] = NE;
}

// bucket cursors: bucket b's append region starts at row_ptr[b*BNODES]
__global__ __launch_bounds__(256) void binit_k(const int* __restrict__ row_ptr, int* __restrict__ bcur) {
  int b = blockIdx.x * 256 + threadIdx.x;
  if (b < NBUK) bcur[b] = row_ptr[b * BNODES];
}

// placement pass 1: append (src, dst_local) into per-bucket regions (temporally dense writes)
__global__ __launch_bounds__(256) void place1_k(const int* __restrict__ src, const int* __restrict__ dst,
                                                int* __restrict__ bcur, int2* __restrict__ staging) {
  const int tid = blockIdx.x * 256 + threadIdx.x;
  const int stride = gridDim.x * 256;
  for (int e = tid; e < NE; e += stride) {
    int d = dst[e];
    int s = src[e];
    int b = d / BNODES;
    int p = atomicAdd(&bcur[b], 1);
    staging[p] = make_int2(s, d - b * BNODES);
  }
}

// placement pass 2: one block per bucket; LDS cursors; final writes land in a ~13KB window (amp ~1)
__global__ __launch_bounds__(256) void place2_k(const int* __restrict__ row_ptr,
                                                const int2* __restrict__ staging, int* __restrict__ ssorted) {
  __shared__ int cur[BNODES];
  const int b = blockIdx.x;
  const int t = threadIdx.x;
  const int nbase = b * BNODES;
  if (t < BNODES) cur[t] = row_ptr[nbase + t];
  __syncthreads();
  const int lo = row_ptr[nbase];
  const int hi = row_ptr[nbase + BNODES];
  for (int i = lo + t; i < hi; i += 256) {
    int2 v = staging[i];
    int p = atomicAdd(&cur[v.y], 1);
    ssorted[p] = v.x;
  }
}

// ---------- fp32 -> bf16 hi/lo split ----------
__global__ __launch_bounds__(256) void split_k(const float* __restrict__ h,
                                               u16* __restrict__ xh, u16* __restrict__ xl) {
  int i = blockIdx.x * 256 + threadIdx.x;
  float4 v = reinterpret_cast<const float4*>(h)[i];
  ushort4 hv, lv;
  hv.x = f2bf(v.x); lv.x = f2bf(v.x - b2f(hv.x));
  hv.y = f2bf(v.y); lv.y = f2bf(v.y - b2f(hv.y));
  hv.z = f2bf(v.z); lv.z = f2bf(v.z - b2f(hv.z));
  hv.w = f2bf(v.w); lv.w = f2bf(v.w - b2f(hv.w));
  reinterpret_cast<ushort4*>(xh)[i] = hv;
  reinterpret_cast<ushort4*>(xl)[i] = lv;
}

// ---------- weight transpose + split: W[128][J] -> Wt[Jpad][128] hi/lo ----------
__global__ __launch_bounds__(256) void wprep_k(const float* __restrict__ W, int J, int Jpad,
                                               u16* __restrict__ wh, u16* __restrict__ wl) {
  int idx = blockIdx.x * 256 + threadIdx.x;
  if (idx >= Jpad * 128) return;
  int j = idx >> 7, k = idx & 127;
  float v = (j < J) ? W[k * J + j] : 0.f;
  u16 hv = f2bf(v);
  wh[idx] = hv;
  wl[idx] = f2bf(v - b2f(hv));
}

// ---------- mean aggregation: one wave64 per node, 2 bf16 feats/lane ----------
__global__ __launch_bounds__(256) void agg_k(const u16* __restrict__ x, const int* __restrict__ row_ptr,
                                             const int* __restrict__ ss,
                                             u16* __restrict__ agg_hi, u16* __restrict__ agg_lo) {
  int gid = blockIdx.x * 256 + threadIdx.x;
  int node = gid >> 6;
  int lane = threadIdx.x & 63;
  if (node >= NN) return;
  int s0 = row_ptr[node], s1 = row_ptr[node + 1];
  float ax = 0.f, ay = 0.f;
  int e = s0;
  for (; e + 2 <= s1; e += 2) {
    int sA = ss[e], sB = ss[e + 1];
    unsigned a = *reinterpret_cast<const unsigned*>(x + (size_t)sA * 128 + lane * 2);
    unsigned b = *reinterpret_cast<const unsigned*>(x + (size_t)sB * 128 + lane * 2);
    ax += bflo(a) + bflo(b);
    ay += bfhi(a) + bfhi(b);
  }
  if (e < s1) {
    unsigned a = *reinterpret_cast<const unsigned*>(x + (size_t)ss[e] * 128 + lane * 2);
    ax += bflo(a);
    ay += bfhi(a);
  }
  float sc = (s1 > s0) ? 1.0f / (float)(s1 - s0) : 0.0f;
  float m0 = ax * sc, m1 = ay * sc;
  u16 h0 = f2bf(m0), h1 = f2bf(m1);
  float l0 = m0 - b2f(h0), l1 = m1 - b2f(h1);
  *reinterpret_cast<unsigned*>(agg_hi + (size_t)node * 128 + lane * 2) = (unsigned)h0 | ((unsigned)h1 << 16);
  *reinterpret_cast<unsigned*>(agg_lo + (size_t)node * 128 + lane * 2) = (unsigned)f2bf(l0) | ((unsigned)f2bf(l1) << 16);
}

// ---------- one split-GEMM pass: acc += A(+A2) @ B over K=128, NT col-tiles ----------
template <int NT, int HAS2>
__device__ __forceinline__ void gpass(const u16* __restrict__ A, const u16* __restrict__ A2,
                                      const u16* __restrict__ B, int r0, int lr, int lg,
                                      f32x4 (&acc)[NT][2]) {
  for (int ks = 0; ks < 4; ++ks) {
    const int ko = ks * 32 + lg * 8;
    bf16x8 a0 = *reinterpret_cast<const bf16x8*>(A + (size_t)(r0 + lr) * 128 + ko);
    bf16x8 a1 = *reinterpret_cast<const bf16x8*>(A + (size_t)(r0 + 16 + lr) * 128 + ko);
    bf16x8 c0 = a0, c1 = a1;
    if (HAS2) {
      c0 = *reinterpret_cast<const bf16x8*>(A2 + (size_t)(r0 + lr) * 128 + ko);
      c1 = *reinterpret_cast<const bf16x8*>(A2 + (size_t)(r0 + 16 + lr) * 128 + ko);
    }
#pragma unroll
    for (int t = 0; t < NT; ++t) {
      bf16x8 b = *reinterpret_cast<const bf16x8*>(B + (size_t)(t * 16 + lr) * 128 + ko);
      acc[t][0] = MFMA16(a0, b, acc[t][0]);
      acc[t][1] = MFMA16(a1, b, acc[t][1]);
      if (HAS2) {
        acc[t][0] = MFMA16(c0, b, acc[t][0]);
        acc[t][1] = MFMA16(c1, b, acc[t][1]);
      }
    }
  }
}

// ---------- fused SAGE layer: split-bf16 MFMA GEMM + bias + LN + ReLU, in-place ----------
__global__ __launch_bounds__(256) void gemm_ln_k(
    const u16* __restrict__ xh, const u16* __restrict__ xl,
    const u16* __restrict__ ah, const u16* __restrict__ al,
    const u16* __restrict__ wsh, const u16* __restrict__ wsl,
    const u16* __restrict__ wnh, const u16* __restrict__ wnl,
    const float* __restrict__ bias, const float* __restrict__ gamma, const float* __restrict__ beta,
    u16* __restrict__ yh, u16* __restrict__ yl) {
  const int lane = threadIdx.x & 63;
  const int wv = threadIdx.x >> 6;
  const int r0 = blockIdx.x * 128 + wv * 32;
  if (r0 >= NN) return;
  const int lr = lane & 15, lg = lane >> 4;

  f32x4 acc[8][2];
#pragma unroll
  for (int t = 0; t < 8; ++t) {
    acc[t][0] = f32x4{0.f, 0.f, 0.f, 0.f};
    acc[t][1] = f32x4{0.f, 0.f, 0.f, 0.f};
  }

  gpass<8, 1>(xh, xl, wsh, r0, lr, lg, acc);
  gpass<8, 0>(xh, xh, wsl, r0, lr, lg, acc);
  gpass<8, 1>(ah, al, wnh, r0, lr, lg, acc);
  gpass<8, 0>(ah, ah, wnl, r0, lr, lg, acc);

  float bcol[8], gcol[8], ecol[8];
#pragma unroll
  for (int t = 0; t < 8; ++t) {
    int c = t * 16 + lr;
    bcol[t] = bias[c];
    gcol[t] = gamma[c];
    ecol[t] = beta[c];
  }

#pragma unroll
  for (int rs = 0; rs < 2; ++rs) {
    float v[8][4];
#pragma unroll
    for (int t = 0; t < 8; ++t)
#pragma unroll
      for (int e = 0; e < 4; ++e) v[t][e] = acc[t][rs][e] + bcol[t];
    float mu[4], inv[4];
#pragma unroll
    for (int e = 0; e < 4; ++e) {
      float s = 0.f;
#pragma unroll
      for (int t = 0; t < 8; ++t) s += v[t][e];
      s += __shfl_xor(s, 1, 64);
      s += __shfl_xor(s, 2, 64);
      s += __shfl_xor(s, 4, 64);
      s += __shfl_xor(s, 8, 64);
      mu[e] = s * 0.0078125f;
    }
#pragma unroll
    for (int e = 0; e < 4; ++e) {
      float q = 0.f;
#pragma unroll
      for (int t = 0; t < 8; ++t) {
        float d = v[t][e] - mu[e];
        q += d * d;
      }
      q += __shfl_xor(q, 1, 64);
      q += __shfl_xor(q, 2, 64);
      q += __shfl_xor(q, 4, 64);
      q += __shfl_xor(q, 8, 64);
      inv[e] = rsqrtf(q * 0.0078125f + EPSV);
    }
#pragma unroll
    for (int t = 0; t < 8; ++t)
#pragma unroll
      for (int e = 0; e < 4; ++e) {
        float o = (v[t][e] - mu[e]) * inv[e] * gcol[t] + ecol[t];
        o = fmaxf(o, 0.f);
        u16 hv = f2bf(o);
        size_t idx = (size_t)(r0 + rs * 16 + lg * 4 + e) * 128 + t * 16 + lr;
        yh[idx] = hv;
        yl[idx] = f2bf(o - b2f(hv));
      }
  }
}

// ---------- final layer: split-bf16 MFMA [N,128]@[128,47] x2 + bias -> fp32 out ----------
__global__ __launch_bounds__(256) void gemm_out_k(
    const u16* __restrict__ xh, const u16* __restrict__ xl,
    const u16* __restrict__ ah, const u16* __restrict__ al,
    const u16* __restrict__ wsh, const u16* __restrict__ wsl,
    const u16* __restrict__ wnh, const u16* __restrict__ wnl,
    const float* __restrict__ bias, float* __restrict__ out) {
  const int lane = threadIdx.x & 63;
  const int wv = threadIdx.x >> 6;
  const int r0 = blockIdx.x * 128 + wv * 32;
  if (r0 >= NN) return;
  const int lr = lane & 15, lg = lane >> 4;

  f32x4 acc[3][2];
#pragma unroll
  for (int t = 0; t < 3; ++t) {
    acc[t][0] = f32x4{0.f, 0.f, 0.f, 0.f};
    acc[t][1] = f32x4{0.f, 0.f, 0.f, 0.f};
  }

  gpass<3, 1>(xh, xl, wsh, r0, lr, lg, acc);
  gpass<3, 0>(xh, xh, wsl, r0, lr, lg, acc);
  gpass<3, 1>(ah, al, wnh, r0, lr, lg, acc);
  gpass<3, 0>(ah, ah, wnl, r0, lr, lg, acc);

  float bcol[3];
#pragma unroll
  for (int t = 0; t < 3; ++t) {
    int c = t * 16 + lr;
    bcol[t] = (c < 47) ? bias[c] : 0.f;
  }
#pragma unroll
  for (int rs = 0; rs < 2; ++rs)
#pragma unroll
    for (int t = 0; t < 3; ++t) {
      int col = t * 16 + lr;
      if (col < 47) {
#pragma unroll
        for (int e = 0; e < 4; ++e) {
          int row = r0 + rs * 16 + lg * 4 + e;
          out[(size_t)row * 47 + col] = acc[t][rs][e] + bcol[t];
        }
      }
    }
}

extern "C" void kernel_launch(void* const* d_in, const int* in_sizes, int n_in,
                              void* d_out, int out_size, void* d_ws, size_t ws_size,
                              hipStream_t stream) {
  const float* h = (const float*)d_in[0];
  const int* src = (const int*)d_in[1];
  const int* dst = (const int*)d_in[2];
  const float* Ws0 = (const float*)d_in[3];
  const float* Wn0 = (const float*)d_in[4];
  const float* b0 = (const float*)d_in[5];
  const float* g0 = (const float*)d_in[6];
  const float* be0 = (const float*)d_in[7];
  const float* Ws1 = (const float*)d_in[8];
  const float* Wn1 = (const float*)d_in[9];
  const float* b1 = (const float*)d_in[10];
  const float* g1 = (const float*)d_in[11];
  const float* be1 = (const float*)d_in[12];
  const float* Ws2 = (const float*)d_in[13];
  const float* Wn2 = (const float*)d_in[14];
  const float* b2 = (const float*)d_in[15];
  float* out = (float*)d_out;

  // workspace layout (all 16B aligned)
  u16* x_hi = (u16*)d_ws;                       // N*128
  u16* x_lo = x_hi + (size_t)NN * 128;          // N*128
  u16* agg_hi = x_lo + (size_t)NN * 128;        // N*128
  u16* agg_lo = agg_hi + (size_t)NN * 128;      // N*128
  int* row_ptr = (int*)(agg_lo + (size_t)NN * 128);  // N+1 (+pad)
  int* ssorted = row_ptr + (NN + 4);            // E
  int* partial = ssorted + NE;                  // SNB (+pad)
  u16* wbuf = (u16*)(partial + 128);
  u16 *w0sh = wbuf, *w0sl = wbuf + 16384, *w0nh = wbuf + 32768, *w0nl = wbuf + 49152;
  u16 *w1sh = wbuf + 65536, *w1sl = wbuf + 81920, *w1nh = wbuf + 98304, *w1nl = wbuf + 114688;
  u16 *w2sh = wbuf + 131072, *w2sl = wbuf + 137216, *w2nh = wbuf + 143360, *w2nl = wbuf + 149504;
  // temps only live during CSR build (before agg_hi/agg_lo are first written):
  int* cnt = (int*)agg_hi;                 // N counts (hist)
  int* bcur = cnt + NN;                    // NBUK bucket cursors
  int2* staging = (int2*)agg_lo;           // E packed (src, dst_local)

  // CSR build: hist -> hierarchical scan -> bucketed two-phase placement
  hipMemsetAsync(cnt, 0, NN * sizeof(int), stream);
  hist_k<<<(NE + 255) / 256, 256, 0, stream>>>(dst, cnt);
  scan1_k<<<SNB, 256, 0, stream>>>(cnt, partial);
  scan2_k<<<1, 128, 0, stream>>>(partial);
  scan3_k<<<SNB, 256, 0, stream>>>(cnt, partial, row_ptr);
  binit_k<<<(NBUK + 255) / 256, 256, 0, stream>>>(row_ptr, bcur);
  place1_k<<<1563, 256, 0, stream>>>(src, dst, bcur, staging);
  place2_k<<<NBUK, 256, 0, stream>>>(row_ptr, staging, ssorted);

  // feature split + weight prep
  split_k<<<(NN * 128 / 4 + 255) / 256, 256, 0, stream>>>(h, x_hi, x_lo);
  wprep_k<<<64, 256, 0, stream>>>(Ws0, 128, 128, w0sh, w0sl);
  wprep_k<<<64, 256, 0, stream>>>(Wn0, 128, 128, w0nh, w0nl);
  wprep_k<<<64, 256, 0, stream>>>(Ws1, 128, 128, w1sh, w1sl);
  wprep_k<<<64, 256, 0, stream>>>(Wn1, 128, 128, w1nh, w1nl);
  wprep_k<<<24, 256, 0, stream>>>(Ws2, 47, 48, w2sh, w2sl);
  wprep_k<<<24, 256, 0, stream>>>(Wn2, 47, 48, w2nh, w2nl);

  const int AGG_GRID = (NN * 64 + 255) / 256;
  const int GEMM_GRID = (NN + 127) / 128;

  // layer 0
  agg_k<<<AGG_GRID, 256, 0, stream>>>(x_hi, row_ptr, ssorted, agg_hi, agg_lo);
  gemm_ln_k<<<GEMM_GRID, 256, 0, stream>>>(x_hi, x_lo, agg_hi, agg_lo,
                                           w0sh, w0sl, w0nh, w0nl, b0, g0, be0, x_hi, x_lo);
  // layer 1
  agg_k<<<AGG_GRID, 256, 0, stream>>>(x_hi, row_ptr, ssorted, agg_hi, agg_lo);
  gemm_ln_k<<<GEMM_GRID, 256, 0, stream>>>(x_hi, x_lo, agg_hi, agg_lo,
                                           w1sh, w1sl, w1nh, w1nl, b1, g1, be1, x_hi, x_lo);
  // layer 2
  agg_k<<<AGG_GRID, 256, 0, stream>>>(x_hi, row_ptr, ssorted, agg_hi, agg_lo);
  gemm_out_k<<<GEMM_GRID, 256, 0, stream>>>(x_hi, x_lo, agg_hi, agg_lo,
                                            w2sh, w2sl, w2nh, w2nl, b2, out);
}

// Round 6
// 634.163 us; speedup vs baseline: 1.7292x; 1.7292x over previous
//
#include <hip/hip_runtime.h>

#define NN 100000
#define NE 1600000
#define EPSV 1e-5f
#define SCHUNK 1024
#define SNB ((NN + SCHUNK - 1) / SCHUNK)  // 98
#define BNODES 200
#define NBUK (NN / BNODES)  // 500
#define EPB 4096
#define NMB ((NE + EPB - 1) / EPB)  // 391
#define MATP 400

typedef unsigned short u16;
typedef __attribute__((ext_vector_type(8))) short bf16x8;
typedef __attribute__((ext_vector_type(4))) float f32x4;

#define MFMA16(a, b, c) __builtin_amdgcn_mfma_f32_16x16x32_bf16(a, b, c, 0, 0, 0)

__device__ __forceinline__ u16 f2bf(float f) {
  unsigned u = __float_as_uint(f);
  unsigned r = u + 0x7fffu + ((u >> 16) & 1u);
  return (u16)(r >> 16);
}
__device__ __forceinline__ float b2f(u16 h) { return __uint_as_float(((unsigned)h) << 16); }
__device__ __forceinline__ float bflo(unsigned u) { return __uint_as_float(u << 16); }
__device__ __forceinline__ float bfhi(unsigned u) { return __uint_as_float(u & 0xffff0000u); }

// ---------- CSR build ----------
__global__ __launch_bounds__(256) void hist_k(const int* __restrict__ dst, int* __restrict__ cnt) {
  int e = blockIdx.x * 256 + threadIdx.x;
  if (e < NE) atomicAdd(&cnt[dst[e]], 1);
}

__global__ __launch_bounds__(256) void scan1_k(const int* __restrict__ cnt, int* __restrict__ partial) {
  __shared__ int ws[4];
  const int t = threadIdx.x;
  const int base = blockIdx.x * SCHUNK;
  int s = 0;
  for (int i = t; i < SCHUNK; i += 256) {
    int idx = base + i;
    s += (idx < NN) ? cnt[idx] : 0;
  }
#pragma unroll
  for (int m = 1; m < 64; m <<= 1) s += __shfl_xor(s, m, 64);
  if ((t & 63) == 0) ws[t >> 6] = s;
  __syncthreads();
  if (t == 0) partial[blockIdx.x] = ws[0] + ws[1] + ws[2] + ws[3];
}

__global__ __launch_bounds__(128) void scan2_k(int* __restrict__ partial) {
  __shared__ int sm[128];
  const int t = threadIdx.x;
  int v = (t < SNB) ? partial[t] : 0;
  sm[t] = v;
  __syncthreads();
  for (int off = 1; off < 128; off <<= 1) {
    int u = (t >= off) ? sm[t - off] : 0;
    __syncthreads();
    sm[t] += u;
    __syncthreads();
  }
  if (t < SNB) partial[t] = sm[t] - v;
}

__global__ __launch_bounds__(256) void scan3_k(const int* __restrict__ cnt, const int* __restrict__ partial,
                                               int* __restrict__ row_ptr) {
  __shared__ int sm[256];
  const int t = threadIdx.x;
  const int base = blockIdx.x * SCHUNK + t * 4;
  int c[4];
  int s = 0;
#pragma unroll
  for (int i = 0; i < 4; ++i) {
    int idx = base + i;
    c[i] = (idx < NN) ? cnt[idx] : 0;
    s += c[i];
  }
  sm[t] = s;
  __syncthreads();
  for (int off = 1; off < 256; off <<= 1) {
    int u = (t >= off) ? sm[t - off] : 0;
    __syncthreads();
    sm[t] += u;
    __syncthreads();
  }
  int run = partial[blockIdx.x] + sm[t] - s;
#pragma unroll
  for (int i = 0; i < 4; ++i) {
    int idx = base + i;
    if (idx < NN) {
      row_ptr[idx] = run;
      run += c[i];
    }
  }
  if (blockIdx.x == 0 && t == 0) row_ptr[NN] = NE;
}

// ---------- block multisplit into 500 buckets (no global atomics) ----------
// pass 1: per-(bucket, block) counts via LDS histogram
__global__ __launch_bounds__(256) void mcount_k(const int* __restrict__ dst, int* __restrict__ mat) {
  __shared__ int cnt[NBUK];
  const int t = threadIdx.x;
  const int blk = blockIdx.x;
  for (int i = t; i < NBUK; i += 256) cnt[i] = 0;
  __syncthreads();
  const int e0 = blk * EPB;
  const int e1 = min(e0 + EPB, NE);
  for (int e = e0 + t; e < e1; e += 256) atomicAdd(&cnt[dst[e] / BNODES], 1);
  __syncthreads();
  for (int i = t; i < NBUK; i += 256) mat[i * MATP + blk] = cnt[i];
}

// pass 2: per-bucket exclusive scan of block counts + bucket base from row_ptr
__global__ __launch_bounds__(256) void mscan_k(int* __restrict__ mat, const int* __restrict__ row_ptr) {
  __shared__ int sm[512];
  const int b = blockIdx.x;
  const int t = threadIdx.x;
  sm[t] = (t < NMB) ? mat[b * MATP + t] : 0;
  sm[t + 256] = (t + 256 < NMB) ? mat[b * MATP + t + 256] : 0;
  __syncthreads();
  for (int off = 1; off < 512; off <<= 1) {
    int a0 = (t >= off) ? sm[t - off] : 0;
    int a1 = (t + 256 >= off) ? sm[t + 256 - off] : 0;
    __syncthreads();
    sm[t] += a0;
    sm[t + 256] += a1;
    __syncthreads();
  }
  const int base = row_ptr[b * BNODES];
  if (t < NMB) mat[b * MATP + t] = base + ((t == 0) ? 0 : sm[t - 1]);
  if (t + 256 < NMB) mat[b * MATP + t + 256] = base + sm[t + 255];
}

// pass 3: re-read edges, append to staging via LDS cursors (bursty dense writes)
__global__ __launch_bounds__(256) void mscatter_k(const int* __restrict__ src, const int* __restrict__ dst,
                                                  const int* __restrict__ mat, int2* __restrict__ staging) {
  __shared__ int off[NBUK];
  const int t = threadIdx.x;
  const int blk = blockIdx.x;
  for (int i = t; i < NBUK; i += 256) off[i] = mat[i * MATP + blk];
  __syncthreads();
  const int e0 = blk * EPB;
  const int e1 = min(e0 + EPB, NE);
  for (int e = e0 + t; e < e1; e += 256) {
    int d = dst[e];
    int s = src[e];
    int b = d / BNODES;
    int p = atomicAdd(&off[b], 1);
    staging[p] = make_int2(s, d - b * BNODES);
  }
}

// pass 4: one block per bucket; LDS node cursors; final scatter lands in a ~13KB window
__global__ __launch_bounds__(256) void place2_k(const int* __restrict__ row_ptr,
                                                const int2* __restrict__ staging, int* __restrict__ ssorted) {
  __shared__ int cur[BNODES];
  const int b = blockIdx.x;
  const int t = threadIdx.x;
  const int nbase = b * BNODES;
  if (t < BNODES) cur[t] = row_ptr[nbase + t];
  __syncthreads();
  const int lo = row_ptr[nbase];
  const int hi = row_ptr[nbase + BNODES];
  for (int i = lo + t; i < hi; i += 256) {
    int2 v = staging[i];
    int p = atomicAdd(&cur[v.y], 1);
    ssorted[p] = v.x;
  }
}

// ---------- fp32 -> bf16 hi/lo split ----------
__global__ __launch_bounds__(256) void split_k(const float* __restrict__ h,
                                               u16* __restrict__ xh, u16* __restrict__ xl) {
  int i = blockIdx.x * 256 + threadIdx.x;
  float4 v = reinterpret_cast<const float4*>(h)[i];
  ushort4 hv, lv;
  hv.x = f2bf(v.x); lv.x = f2bf(v.x - b2f(hv.x));
  hv.y = f2bf(v.y); lv.y = f2bf(v.y - b2f(hv.y));
  hv.z = f2bf(v.z); lv.z = f2bf(v.z - b2f(hv.z));
  hv.w = f2bf(v.w); lv.w = f2bf(v.w - b2f(hv.w));
  reinterpret_cast<ushort4*>(xh)[i] = hv;
  reinterpret_cast<ushort4*>(xl)[i] = lv;
}

// ---------- weight transpose + split: W[128][J] -> Wt[Jpad][128] hi/lo ----------
__global__ __launch_bounds__(256) void wprep_k(const float* __restrict__ W, int J, int Jpad,
                                               u16* __restrict__ wh, u16* __restrict__ wl) {
  int idx = blockIdx.x * 256 + threadIdx.x;
  if (idx >= Jpad * 128) return;
  int j = idx >> 7, k = idx & 127;
  float v = (j < J) ? W[k * J + j] : 0.f;
  u16 hv = f2bf(v);
  wh[idx] = hv;
  wl[idx] = f2bf(v - b2f(hv));
}

// ---------- mean aggregation: one wave64 per node, 2 bf16 feats/lane ----------
__global__ __launch_bounds__(256) void agg_k(const u16* __restrict__ x, const int* __restrict__ row_ptr,
                                             const int* __restrict__ ss,
                                             u16* __restrict__ agg_hi, u16* __restrict__ agg_lo) {
  int gid = blockIdx.x * 256 + threadIdx.x;
  int node = gid >> 6;
  int lane = threadIdx.x & 63;
  if (node >= NN) return;
  int s0 = row_ptr[node], s1 = row_ptr[node + 1];
  float ax = 0.f, ay = 0.f;
  int e = s0;
  for (; e + 2 <= s1; e += 2) {
    int sA = ss[e], sB = ss[e + 1];
    unsigned a = *reinterpret_cast<const unsigned*>(x + (size_t)sA * 128 + lane * 2);
    unsigned b = *reinterpret_cast<const unsigned*>(x + (size_t)sB * 128 + lane * 2);
    ax += bflo(a) + bflo(b);
    ay += bfhi(a) + bfhi(b);
  }
  if (e < s1) {
    unsigned a = *reinterpret_cast<const unsigned*>(x + (size_t)ss[e] * 128 + lane * 2);
    ax += bflo(a);
    ay += bfhi(a);
  }
  float sc = (s1 > s0) ? 1.0f / (float)(s1 - s0) : 0.0f;
  float m0 = ax * sc, m1 = ay * sc;
  u16 h0 = f2bf(m0), h1 = f2bf(m1);
  float l0 = m0 - b2f(h0), l1 = m1 - b2f(h1);
  *reinterpret_cast<unsigned*>(agg_hi + (size_t)node * 128 + lane * 2) = (unsigned)h0 | ((unsigned)h1 << 16);
  *reinterpret_cast<unsigned*>(agg_lo + (size_t)node * 128 + lane * 2) = (unsigned)f2bf(l0) | ((unsigned)f2bf(l1) << 16);
}

// ---------- one split-GEMM pass: acc += A(+A2) @ B over K=128, NT col-tiles ----------
template <int NT, int HAS2>
__device__ __forceinline__ void gpass(const u16* __restrict__ A, const u16* __restrict__ A2,
                                      const u16* __restrict__ B, int r0, int lr, int lg,
                                      f32x4 (&acc)[NT][2]) {
  for (int ks = 0; ks < 4; ++ks) {
    const int ko = ks * 32 + lg * 8;
    bf16x8 a0 = *reinterpret_cast<const bf16x8*>(A + (size_t)(r0 + lr) * 128 + ko);
    bf16x8 a1 = *reinterpret_cast<const bf16x8*>(A + (size_t)(r0 + 16 + lr) * 128 + ko);
    bf16x8 c0 = a0, c1 = a1;
    if (HAS2) {
      c0 = *reinterpret_cast<const bf16x8*>(A2 + (size_t)(r0 + lr) * 128 + ko);
      c1 = *reinterpret_cast<const bf16x8*>(A2 + (size_t)(r0 + 16 + lr) * 128 + ko);
    }
#pragma unroll
    for (int t = 0; t < NT; ++t) {
      bf16x8 b = *reinterpret_cast<const bf16x8*>(B + (size_t)(t * 16 + lr) * 128 + ko);
      acc[t][0] = MFMA16(a0, b, acc[t][0]);
      acc[t][1] = MFMA16(a1, b, acc[t][1]);
      if (HAS2) {
        acc[t][0] = MFMA16(c0, b, acc[t][0]);
        acc[t][1] = MFMA16(c1, b, acc[t][1]);
      }
    }
  }
}

// ---------- fused SAGE layer: split-bf16 MFMA GEMM + bias + LN + ReLU, in-place ----------
__global__ __launch_bounds__(256) void gemm_ln_k(
    const u16* __restrict__ xh, const u16* __restrict__ xl,
    const u16* __restrict__ ah, const u16* __restrict__ al,
    const u16* __restrict__ wsh, const u16* __restrict__ wsl,
    const u16* __restrict__ wnh, const u16* __restrict__ wnl,
    const float* __restrict__ bias, const float* __restrict__ gamma, const float* __restrict__ beta,
    u16* __restrict__ yh, u16* __restrict__ yl) {
  const int lane = threadIdx.x & 63;
  const int wv = threadIdx.x >> 6;
  const int r0 = blockIdx.x * 128 + wv * 32;
  if (r0 >= NN) return;
  const int lr = lane & 15, lg = lane >> 4;

  f32x4 acc[8][2];
#pragma unroll
  for (int t = 0; t < 8; ++t) {
    acc[t][0] = f32x4{0.f, 0.f, 0.f, 0.f};
    acc[t][1] = f32x4{0.f, 0.f, 0.f, 0.f};
  }

  gpass<8, 1>(xh, xl, wsh, r0, lr, lg, acc);
  gpass<8, 0>(xh, xh, wsl, r0, lr, lg, acc);
  gpass<8, 1>(ah, al, wnh, r0, lr, lg, acc);
  gpass<8, 0>(ah, ah, wnl, r0, lr, lg, acc);

  float bcol[8], gcol[8], ecol[8];
#pragma unroll
  for (int t = 0; t < 8; ++t) {
    int c = t * 16 + lr;
    bcol[t] = bias[c];
    gcol[t] = gamma[c];
    ecol[t] = beta[c];
  }

#pragma unroll
  for (int rs = 0; rs < 2; ++rs) {
    float v[8][4];
#pragma unroll
    for (int t = 0; t < 8; ++t)
#pragma unroll
      for (int e = 0; e < 4; ++e) v[t][e] = acc[t][rs][e] + bcol[t];
    float mu[4], inv[4];
#pragma unroll
    for (int e = 0; e < 4; ++e) {
      float s = 0.f;
#pragma unroll
      for (int t = 0; t < 8; ++t) s += v[t][e];
      s += __shfl_xor(s, 1, 64);
      s += __shfl_xor(s, 2, 64);
      s += __shfl_xor(s, 4, 64);
      s += __shfl_xor(s, 8, 64);
      mu[e] = s * 0.0078125f;
    }
#pragma unroll
    for (int e = 0; e < 4; ++e) {
      float q = 0.f;
#pragma unroll
      for (int t = 0; t < 8; ++t) {
        float d = v[t][e] - mu[e];
        q += d * d;
      }
      q += __shfl_xor(q, 1, 64);
      q += __shfl_xor(q, 2, 64);
      q += __shfl_xor(q, 4, 64);
      q += __shfl_xor(q, 8, 64);
      inv[e] = rsqrtf(q * 0.0078125f + EPSV);
    }
#pragma unroll
    for (int t = 0; t < 8; ++t)
#pragma unroll
      for (int e = 0; e < 4; ++e) {
        float o = (v[t][e] - mu[e]) * inv[e] * gcol[t] + ecol[t];
        o = fmaxf(o, 0.f);
        u16 hv = f2bf(o);
        size_t idx = (size_t)(r0 + rs * 16 + lg * 4 + e) * 128 + t * 16 + lr;
        yh[idx] = hv;
        yl[idx] = f2bf(o - b2f(hv));
      }
  }
}

// ---------- final layer: split-bf16 MFMA [N,128]@[128,47] x2 + bias -> fp32 out ----------
__global__ __launch_bounds__(256) void gemm_out_k(
    const u16* __restrict__ xh, const u16* __restrict__ xl,
    const u16* __restrict__ ah, const u16* __restrict__ al,
    const u16* __restrict__ wsh, const u16* __restrict__ wsl,
    const u16* __restrict__ wnh, const u16* __restrict__ wnl,
    const float* __restrict__ bias, float* __restrict__ out) {
  const int lane = threadIdx.x & 63;
  const int wv = threadIdx.x >> 6;
  const int r0 = blockIdx.x * 128 + wv * 32;
  if (r0 >= NN) return;
  const int lr = lane & 15, lg = lane >> 4;

  f32x4 acc[3][2];
#pragma unroll
  for (int t = 0; t < 3; ++t) {
    acc[t][0] = f32x4{0.f, 0.f, 0.f, 0.f};
    acc[t][1] = f32x4{0.f, 0.f, 0.f, 0.f};
  }

  gpass<3, 1>(xh, xl, wsh, r0, lr, lg, acc);
  gpass<3, 0>(xh, xh, wsl, r0, lr, lg, acc);
  gpass<3, 1>(ah, al, wnh, r0, lr, lg, acc);
  gpass<3, 0>(ah, ah, wnl, r0, lr, lg, acc);

  float bcol[3];
#pragma unroll
  for (int t = 0; t < 3; ++t) {
    int c = t * 16 + lr;
    bcol[t] = (c < 47) ? bias[c] : 0.f;
  }
#pragma unroll
  for (int rs = 0; rs < 2; ++rs)
#pragma unroll
    for (int t = 0; t < 3; ++t) {
      int col = t * 16 + lr;
      if (col < 47) {
#pragma unroll
        for (int e = 0; e < 4; ++e) {
          int row = r0 + rs * 16 + lg * 4 + e;
          out[(size_t)row * 47 + col] = acc[t][rs][e] + bcol[t];
        }
      }
    }
}

extern "C" void kernel_launch(void* const* d_in, const int* in_sizes, int n_in,
                              void* d_out, int out_size, void* d_ws, size_t ws_size,
                              hipStream_t stream) {
  const float* h = (const float*)d_in[0];
  const int* src = (const int*)d_in[1];
  const int* dst = (const int*)d_in[2];
  const float* Ws0 = (const float*)d_in[3];
  const float* Wn0 = (const float*)d_in[4];
  const float* b0 = (const float*)d_in[5];
  const float* g0 = (const float*)d_in[6];
  const float* be0 = (const float*)d_in[7];
  const float* Ws1 = (const float*)d_in[8];
  const float* Wn1 = (const float*)d_in[9];
  const float* b1 = (const float*)d_in[10];
  const float* g1 = (const float*)d_in[11];
  const float* be1 = (const float*)d_in[12];
  const float* Ws2 = (const float*)d_in[13];
  const float* Wn2 = (const float*)d_in[14];
  const float* b2 = (const float*)d_in[15];
  float* out = (float*)d_out;

  // workspace layout (all 16B aligned)
  u16* x_hi = (u16*)d_ws;                       // N*128
  u16* x_lo = x_hi + (size_t)NN * 128;          // N*128
  u16* agg_hi = x_lo + (size_t)NN * 128;        // N*128
  u16* agg_lo = agg_hi + (size_t)NN * 128;      // N*128
  int* row_ptr = (int*)(agg_lo + (size_t)NN * 128);  // N+1 (+pad)
  int* ssorted = row_ptr + (NN + 4);            // E
  int* partial = ssorted + NE;                  // SNB (+pad)
  u16* wbuf = (u16*)(partial + 128);
  u16 *w0sh = wbuf, *w0sl = wbuf + 16384, *w0nh = wbuf + 32768, *w0nl = wbuf + 49152;
  u16 *w1sh = wbuf + 65536, *w1sl = wbuf + 81920, *w1nh = wbuf + 98304, *w1nl = wbuf + 114688;
  u16 *w2sh = wbuf + 131072, *w2sl = wbuf + 137216, *w2nh = wbuf + 143360, *w2nl = wbuf + 149504;
  // temps only live during CSR build (before agg_hi/agg_lo are first written):
  int* cnt = (int*)agg_hi;                 // N counts (hist)
  int* mat = cnt + NN;                     // NBUK*MATP (bucket,block) counts/offsets (800 KB)
  int2* staging = (int2*)agg_lo;           // E packed (src, dst_local)

  // CSR build: hist -> hierarchical scan -> atomic-free multisplit -> bucket scatter
  hipMemsetAsync(cnt, 0, NN * sizeof(int), stream);
  hist_k<<<(NE + 255) / 256, 256, 0, stream>>>(dst, cnt);
  scan1_k<<<SNB, 256, 0, stream>>>(cnt, partial);
  scan2_k<<<1, 128, 0, stream>>>(partial);
  scan3_k<<<SNB, 256, 0, stream>>>(cnt, partial, row_ptr);
  mcount_k<<<NMB, 256, 0, stream>>>(dst, mat);
  mscan_k<<<NBUK, 256, 0, stream>>>(mat, row_ptr);
  mscatter_k<<<NMB, 256, 0, stream>>>(src, dst, mat, staging);
  place2_k<<<NBUK, 256, 0, stream>>>(row_ptr, staging, ssorted);

  // feature split + weight prep
  split_k<<<(NN * 128 / 4 + 255) / 256, 256, 0, stream>>>(h, x_hi, x_lo);
  wprep_k<<<64, 256, 0, stream>>>(Ws0, 128, 128, w0sh, w0sl);
  wprep_k<<<64, 256, 0, stream>>>(Wn0, 128, 128, w0nh, w0nl);
  wprep_k<<<64, 256, 0, stream>>>(Ws1, 128, 128, w1sh, w1sl);
  wprep_k<<<64, 256, 0, stream>>>(Wn1, 128, 128, w1nh, w1nl);
  wprep_k<<<24, 256, 0, stream>>>(Ws2, 47, 48, w2sh, w2sl);
  wprep_k<<<24, 256, 0, stream>>>(Wn2, 47, 48, w2nh, w2nl);

  const int AGG_GRID = (NN * 64 + 255) / 256;
  const int GEMM_GRID = (NN + 127) / 128;

  // layer 0
  agg_k<<<AGG_GRID, 256, 0, stream>>>(x_hi, row_ptr, ssorted, agg_hi, agg_lo);
  gemm_ln_k<<<GEMM_GRID, 256, 0, stream>>>(x_hi, x_lo, agg_hi, agg_lo,
                                           w0sh, w0sl, w0nh, w0nl, b0, g0, be0, x_hi, x_lo);
  // layer 1
  agg_k<<<AGG_GRID, 256, 0, stream>>>(x_hi, row_ptr, ssorted, agg_hi, agg_lo);
  gemm_ln_k<<<GEMM_GRID, 256, 0, stream>>>(x_hi, x_lo, agg_hi, agg_lo,
                                           w1sh, w1sl, w1nh, w1nl, b1, g1, be1, x_hi, x_lo);
  // layer 2
  agg_k<<<AGG_GRID, 256, 0, stream>>>(x_hi, row_ptr, ssorted, agg_hi, agg_lo);
  gemm_out_k<<<GEMM_GRID, 256, 0, stream>>>(x_hi, x_lo, agg_hi, agg_lo,
                                            w2sh, w2sl, w2nh, w2nl, b2, out);
}